// Round 1
// 126.708 us; speedup vs baseline: 1.0764x; 1.0764x over previous
//
#include <hip/hip_runtime.h>

// RewardTripletLoss: sim/gram GEMMs (bf16 MFMA) + per-row loss + FastAP rewards.
// R4: merge loss_kernel + fastap_kernel into one block-per-row kernel (lossap).
// loss (VALU/HBM-bound) hides under fastap's LDS-atomic storm; one fewer launch;
// block emits loss_i*(1-reward_i) directly so final reads one 16KB array.

#define N_ROWS 4096
#define DIM 128
#define TILE 128
#define L_BINS 1601

typedef __bf16 bf16x8 __attribute__((ext_vector_type(8)));
typedef float f32x4 __attribute__((ext_vector_type(4)));

__device__ __forceinline__ unsigned short f32_to_bf16(float f) {
    unsigned int u = __float_as_uint(f);
    u = (u + 0x7FFFu + ((u >> 16) & 1u)) >> 16;
    return (unsigned short)u;
}

__device__ __forceinline__ float bf16_lo(unsigned int u) {
    return __uint_as_float(u << 16);
}
__device__ __forceinline__ float bf16_hi(unsigned int u) {
    return __uint_as_float(u & 0xFFFF0000u);
}

__device__ __forceinline__ void unpack8(uint4 pk, float* s) {
    s[0] = bf16_lo(pk.x); s[1] = bf16_hi(pk.x);
    s[2] = bf16_lo(pk.y); s[3] = bf16_hi(pk.y);
    s[4] = bf16_lo(pk.z); s[5] = bf16_hi(pk.z);
    s[6] = bf16_lo(pk.w); s[7] = bf16_hi(pk.w);
}

// Async global->LDS, 16B per lane. LDS dest is wave-uniform base + lane*16.
__device__ __forceinline__ void async_copy16(const void* g, void* l) {
    __builtin_amdgcn_global_load_lds(
        (const __attribute__((address_space(1))) unsigned int*)g,
        (__attribute__((address_space(3))) unsigned int*)l, 16, 0, 0);
}

// Both f32->bf16 conversions in one launch.
__global__ __launch_bounds__(256) void cvt2_kernel(const float4* __restrict__ a,
                                                   const float4* __restrict__ b,
                                                   ushort4* __restrict__ oa,
                                                   ushort4* __restrict__ ob,
                                                   int nvec) {
    for (int idx = blockIdx.x * 256 + threadIdx.x; idx < 2 * nvec; idx += gridDim.x * 256) {
        bool second = idx >= nvec;
        int k = second ? idx - nvec : idx;
        float4 v = second ? b[k] : a[k];
        ushort4 o;
        o.x = f32_to_bf16(v.x); o.y = f32_to_bf16(v.y);
        o.z = f32_to_bf16(v.z); o.w = f32_to_bf16(v.w);
        if (second) ob[k] = o; else oa[k] = o;
    }
}

// C[i][j] = sum_k A[i][k]*Bz[j][k]. Grid (32,32,2): z=0 -> B0->C0 (sim), z=1 -> B1->C1 (gram).
__global__ __launch_bounds__(256) void gemm_tile_kernel(const unsigned short* __restrict__ A,
                                                        const unsigned short* __restrict__ B0,
                                                        const unsigned short* __restrict__ B1,
                                                        unsigned short* __restrict__ C0,
                                                        unsigned short* __restrict__ C1,
                                                        int N) {
    __shared__ unsigned short As[TILE * DIM];  // 32 KB (tile contiguous in global)
    __shared__ unsigned short Bs[TILE * DIM];  // 32 KB
    int w = threadIdx.x >> 6;
    int lane = threadIdx.x & 63;
    int tm = blockIdx.y, tn = blockIdx.x;
    const unsigned short* B = blockIdx.z ? B1 : B0;
    unsigned short* C = blockIdx.z ? C1 : C0;

    const char* ga = (const char*)(A + (size_t)tm * TILE * DIM);
    const char* gb = (const char*)(B + (size_t)tn * TILE * DIM);
#pragma unroll
    for (int it = 0; it < 8; ++it) {
        int off = (w * 8 + it) * 1024;  // wave-chunk of 1KB (64 lanes x 16B)
        async_copy16(ga + off + lane * 16, (char*)As + off);
        async_copy16(gb + off + lane * 16, (char*)Bs + off);
    }
    __syncthreads();

    int wm = (w & 1) * 64;
    int wn = (w >> 1) * 64;
    int quad = lane >> 4;
    int l15 = lane & 15;

    f32x4 acc[4][4] = {};
#pragma unroll
    for (int kk = 0; kk < 4; ++kk) {
        int kb = kk * 32 + quad * 8;
        bf16x8 af[4], bfr[4];
#pragma unroll
        for (int mi = 0; mi < 4; ++mi)
            af[mi] = *(const bf16x8*)&As[(wm + mi * 16 + l15) * DIM + kb];
#pragma unroll
        for (int ni = 0; ni < 4; ++ni)
            bfr[ni] = *(const bf16x8*)&Bs[(wn + ni * 16 + l15) * DIM + kb];
#pragma unroll
        for (int mi = 0; mi < 4; ++mi)
#pragma unroll
            for (int ni = 0; ni < 4; ++ni)
                acc[mi][ni] = __builtin_amdgcn_mfma_f32_16x16x32_bf16(af[mi], bfr[ni], acc[mi][ni], 0, 0, 0);
    }

#pragma unroll
    for (int mi = 0; mi < 4; ++mi) {
        int row0 = tm * TILE + wm + mi * 16 + quad * 4;
#pragma unroll
        for (int ni = 0; ni < 4; ++ni) {
            int col = tn * TILE + wn + ni * 16 + l15;
#pragma unroll
            for (int r = 0; r < 4; ++r)
                C[(size_t)(row0 + r) * N + col] = f32_to_bf16(acc[mi][ni][r]);
        }
    }
}

// Merged loss + FastAP: one block per row i.
// - loss: block-per-row, 16 sim elems/thread register-resident; block max via
//   shfl + LDS; second pass from registers. (VALU + HBM pipe)
// - fastap: u64 packed histogram (pos<<32 | all), 2 native ds_add_u64 per elem,
//   shuffle chunked scan. (LDS-atomic pipe)
// The two interleave within a block -> loss hides under the atomic storm.
// 4 barriers total. Emits contrib[i] = loss_i * (1 - reward_i).
__global__ __launch_bounds__(256) void lossap_kernel(const unsigned short* __restrict__ sim,
                                                     const unsigned short* __restrict__ gram,
                                                     const int* __restrict__ tcol,
                                                     const int* __restrict__ trow,
                                                     const int* __restrict__ rlab,
                                                     float* __restrict__ contrib,
                                                     int n) {
    __shared__ unsigned long long hist[L_BINS];  // 12.8 KB
    __shared__ unsigned long long wsum[4];
    __shared__ float pmx[4], nmx[4], lsum[4], apw[4];
    __shared__ int npw[4];
    int i = blockIdx.x;
    int t = threadIdx.x;
    int w = t >> 6, lane = t & 63;

    for (int b = t; b < L_BINS; b += 256) hist[b] = 0ull;

    int myt = tcol[i];
    int li = rlab[i];
    const uint4* simv = (const uint4*)(sim + (size_t)i * n);
    const uint4* grav = (const uint4*)(gram + (size_t)i * n);
    const int4* trv = (const int4*)trow;
    const int4* rlv = (const int4*)rlab;

    // Issue ALL global loads up front (sim row, gram row, both label arrays)
    // so HBM latency hides under hist-zero + maxima pass.
    uint4 spk[2], gpk[2];
    int4 tl[4], rl[4];
#pragma unroll
    for (int vv = 0; vv < 2; ++vv) {
        int vi = vv * 256 + t;
        spk[vv] = simv[vi];
        gpk[vv] = grav[vi];
        tl[2 * vv] = trv[2 * vi];
        tl[2 * vv + 1] = trv[2 * vi + 1];
        rl[2 * vv] = rlv[2 * vi];
        rl[2 * vv + 1] = rlv[2 * vi + 1];
    }

    // Pass 1: per-thread pos/neg maxima + selection masks from sim.
    float pmax = -3e38f, nmax = -3e38f;
    unsigned int posm = 0, negm = 0;
#pragma unroll
    for (int vv = 0; vv < 2; ++vv) {
        int vi = vv * 256 + t;
        float s[8];
        unpack8(spk[vv], s);
        int lab[8] = {tl[2 * vv].x, tl[2 * vv].y, tl[2 * vv].z, tl[2 * vv].w,
                      tl[2 * vv + 1].x, tl[2 * vv + 1].y, tl[2 * vv + 1].z, tl[2 * vv + 1].w};
#pragma unroll
        for (int k = 0; k < 8; ++k) {
            int j = vi * 8 + k;
            bool same = (lab[k] == myt);
            bool posf = same && (j != i);
            if (posf) pmax = fmaxf(pmax, s[k]);
            if (!same) nmax = fmaxf(nmax, s[k]);
            posm |= ((unsigned int)posf) << (vv * 8 + k);
            negm |= ((unsigned int)(!same)) << (vv * 8 + k);
        }
    }
    __syncthreads();  // hist zeroed

    // FastAP histogram: 2 ds_add_u64 per elem, from registers.
    int npos = 0;
#pragma unroll
    for (int vv = 0; vv < 2; ++vv) {
        int vi = vv * 256 + t;
        float s[8];
        unpack8(gpk[vv], s);
        int lab[8] = {rl[2 * vv].x, rl[2 * vv].y, rl[2 * vv].z, rl[2 * vv].w,
                      rl[2 * vv + 1].x, rl[2 * vv + 1].y, rl[2 * vv + 1].z, rl[2 * vv + 1].w};
#pragma unroll
        for (int k = 0; k < 8; ++k) {
            int j = vi * 8 + k;
            float d2 = fminf(fmaxf(2.f - 2.f * s[k], 0.f), 4.f);
            float tt = d2 * 400.0f;  // / (4/1600)
            float fl = floorf(tt);
            int i0 = (int)fl;
            if (i0 > L_BINS - 1) i0 = L_BINS - 1;
            int i1 = i0 + 1;
            if (i1 > L_BINS - 1) i1 = L_BINS - 1;
            unsigned int w1 = (unsigned int)((tt - fl) * 65536.0f);
            unsigned int w0 = 65536u - w1;
            bool diag = (j == i);
            if (diag) { w0 = 0u; w1 = 0u; }
            bool posf = (lab[k] == li) && !diag;
            unsigned long long hi = posf ? 1ull : 0ull;
            atomicAdd(&hist[i0], (unsigned long long)w0 | ((hi * w0) << 32));
            atomicAdd(&hist[i1], (unsigned long long)w1 | ((hi * w1) << 32));
            npos += posf ? 1 : 0;
        }
    }

    // Wave maxima reduce (VALU, overlaps atomic drain).
#pragma unroll
    for (int off = 32; off > 0; off >>= 1) {
        pmax = fmaxf(pmax, __shfl_xor(pmax, off));
        nmax = fmaxf(nmax, __shfl_xor(nmax, off));
    }
    if (lane == 0) { pmx[w] = pmax; nmx[w] = nmax; }
    __syncthreads();  // atomics complete + wave maxima visible

    pmax = fmaxf(fmaxf(pmx[0], pmx[1]), fmaxf(pmx[2], pmx[3]));
    nmax = fmaxf(fmaxf(nmx[0], nmx[1]), fmaxf(nmx[2], nmx[3]));

    // Pass 2: loss sums from registers.
    float thr_n = nmax + 0.1f;               // pos selected when sim < neg_max + margin
    float thr_p = fmaxf(0.6f, pmax) - 0.1f;  // neg selected when sim > thr
    float pl = 0.f, nl = 0.f;
#pragma unroll
    for (int vv = 0; vv < 2; ++vv) {
        float s[8];
        unpack8(spk[vv], s);
#pragma unroll
        for (int k = 0; k < 8; ++k) {
            int bit = vv * 8 + k;
            bool posf = (posm >> bit) & 1u;
            bool negf = (negm >> bit) & 1u;
            pl += (posf && s[k] < thr_n) ? 1.f - s[k] : 0.f;
            nl += (negf && s[k] > thr_p) ? s[k] : 0.f;
        }
    }
    float tot = pl + nl;
#pragma unroll
    for (int off = 32; off > 0; off >>= 1) tot += __shfl_xor(tot, off);

    // Chunked scan: 7 bins/thread; shuffle inclusive scan of thread totals.
    const int CH = 7;
    int base = t * CH;
    unsigned long long lc[CH];
    unsigned long long run = 0ull;
#pragma unroll
    for (int k = 0; k < CH; ++k) {
        int idx = base + k;
        unsigned long long h = (idx < L_BINS) ? hist[idx] : 0ull;
        run += h;
        lc[k] = run;
    }
    unsigned long long tsum = run;
    unsigned long long sc = tsum;
#pragma unroll
    for (int off = 1; off < 64; off <<= 1) {
        unsigned long long v2 = __shfl_up(sc, off);
        if (lane >= off) sc += v2;
    }
    if (lane == 63) wsum[w] = sc;
    if (lane == 0) lsum[w] = tot;
    __syncthreads();
    unsigned long long woff = 0ull;
    for (int ww = 0; ww < w; ++ww) woff += wsum[ww];
    unsigned long long throff = woff + sc - tsum;  // exclusive offset for this thread

    float ap = 0.f;
#pragma unroll
    for (int k = 0; k < CH; ++k) {
        int idx = base + k;
        if (idx < L_BINS) {
            unsigned long long h = hist[idx];
            unsigned int hp = (unsigned int)(h >> 32);
            if (hp) {
                unsigned long long cum = lc[k] + throff;
                unsigned int Hp = (unsigned int)(cum >> 32);
                unsigned int Ha = (unsigned int)cum;
                ap += (float)hp * (float)Hp / (float)Ha;
            }
        }
    }
#pragma unroll
    for (int off = 32; off > 0; off >>= 1) {
        ap += __shfl_xor(ap, off);
        npos += __shfl_xor(npos, off);
    }
    if (lane == 0) { apw[w] = ap; npw[w] = npos; }
    __syncthreads();
    if (t == 0) {
        float loss_i = (pmax > -1e30f) ? (lsum[0] + lsum[1] + lsum[2] + lsum[3]) : 0.f;
        float A = apw[0] + apw[1] + apw[2] + apw[3];
        int np = npw[0] + npw[1] + npw[2] + npw[3];
        float reward = (np > 0) ? A * (1.0f / 65536.0f) / (float)np : 0.f;
        contrib[i] = loss_i * (1.f - reward);
    }
}

__global__ __launch_bounds__(256) void final_kernel(const float* __restrict__ contrib,
                                                    float* __restrict__ out, int n) {
    __shared__ float r[256];
    int t = threadIdx.x;
    float s = 0.f;
    for (int j = t; j < n; j += 256) s += contrib[j];
    r[t] = s;
    __syncthreads();
    for (int off = 128; off > 0; off >>= 1) {
        if (t < off) r[t] += r[t + off];
        __syncthreads();
    }
    if (t == 0) out[0] = r[0] / (float)n;
}

extern "C" void kernel_launch(void* const* d_in, const int* in_sizes, int n_in,
                              void* d_out, int out_size, void* d_ws, size_t ws_size,
                              hipStream_t stream) {
    const float* inputs_col = (const float*)d_in[0];
    const int* targets_col = (const int*)d_in[1];
    const float* inputs_row = (const float*)d_in[2];
    const int* targets_row = (const int*)d_in[3];
    const int* reward_labels = (const int*)d_in[4];
    float* out = (float*)d_out;

    const int n = N_ROWS, m = N_ROWS, d = DIM;
    char* ws = (char*)d_ws;
    const size_t MB = 1048576;
    unsigned short* simbuf = (unsigned short*)ws;                 // 32 MB
    unsigned short* grambuf = (unsigned short*)(ws + 32 * MB);    // 32 MB
    unsigned short* Abf = (unsigned short*)(ws + 64 * MB);        // 1 MB
    unsigned short* Rbf = (unsigned short*)(ws + 65 * MB);        // 1 MB
    float* contrib = (float*)(ws + 66 * MB);

    // 1) f32 -> bf16 (both arrays, one launch)
    cvt2_kernel<<<512, 256, 0, stream>>>((const float4*)inputs_col, (const float4*)inputs_row,
                                         (ushort4*)Abf, (ushort4*)Rbf, n * d / 4);

    // 2) sim = col@row^T and gram = col@col^T in one launch
    dim3 ggrid(n / TILE, n / TILE, 2);
    gemm_tile_kernel<<<ggrid, 256, 0, stream>>>(Abf, Rbf, Abf, simbuf, grambuf, m);

    // 3) merged per-row loss + FastAP reward -> contrib[i]
    lossap_kernel<<<n, 256, 0, stream>>>(simbuf, grambuf, targets_col, targets_row,
                                         reward_labels, contrib, n);

    // 4) final scalar
    final_kernel<<<1, 256, 0, stream>>>(contrib, out, n);
}

// Round 2
// 124.809 us; speedup vs baseline: 1.0928x; 1.0152x over previous
//
#include <hip/hip_runtime.h>

// RewardTripletLoss: sim/gram GEMMs (bf16 MFMA) + per-row loss + FastAP rewards.
// R5: histogram u64 -> 2x u32 (all + rare pos). ds_add_u64 has a >=4-way bank
// conflict floor (2 banks/lane, 16 pairs for 64 lanes); u32 has a 2-way floor
// which is free (m136). Positive adds are ~8/4096 per row -> exec-masked branch
// is nearly free. Scan repacks (pos<<32)|all into the same u64 chunked scan.

#define N_ROWS 4096
#define DIM 128
#define TILE 128
#define L_BINS 1601

typedef __bf16 bf16x8 __attribute__((ext_vector_type(8)));
typedef float f32x4 __attribute__((ext_vector_type(4)));

__device__ __forceinline__ unsigned short f32_to_bf16(float f) {
    unsigned int u = __float_as_uint(f);
    u = (u + 0x7FFFu + ((u >> 16) & 1u)) >> 16;
    return (unsigned short)u;
}

__device__ __forceinline__ float bf16_lo(unsigned int u) {
    return __uint_as_float(u << 16);
}
__device__ __forceinline__ float bf16_hi(unsigned int u) {
    return __uint_as_float(u & 0xFFFF0000u);
}

__device__ __forceinline__ void unpack8(uint4 pk, float* s) {
    s[0] = bf16_lo(pk.x); s[1] = bf16_hi(pk.x);
    s[2] = bf16_lo(pk.y); s[3] = bf16_hi(pk.y);
    s[4] = bf16_lo(pk.z); s[5] = bf16_hi(pk.z);
    s[6] = bf16_lo(pk.w); s[7] = bf16_hi(pk.w);
}

// Async global->LDS, 16B per lane. LDS dest is wave-uniform base + lane*16.
__device__ __forceinline__ void async_copy16(const void* g, void* l) {
    __builtin_amdgcn_global_load_lds(
        (const __attribute__((address_space(1))) unsigned int*)g,
        (__attribute__((address_space(3))) unsigned int*)l, 16, 0, 0);
}

// Both f32->bf16 conversions in one launch.
__global__ __launch_bounds__(256) void cvt2_kernel(const float4* __restrict__ a,
                                                   const float4* __restrict__ b,
                                                   ushort4* __restrict__ oa,
                                                   ushort4* __restrict__ ob,
                                                   int nvec) {
    for (int idx = blockIdx.x * 256 + threadIdx.x; idx < 2 * nvec; idx += gridDim.x * 256) {
        bool second = idx >= nvec;
        int k = second ? idx - nvec : idx;
        float4 v = second ? b[k] : a[k];
        ushort4 o;
        o.x = f32_to_bf16(v.x); o.y = f32_to_bf16(v.y);
        o.z = f32_to_bf16(v.z); o.w = f32_to_bf16(v.w);
        if (second) ob[k] = o; else oa[k] = o;
    }
}

// C[i][j] = sum_k A[i][k]*Bz[j][k]. Grid (32,32,2): z=0 -> B0->C0 (sim), z=1 -> B1->C1 (gram).
__global__ __launch_bounds__(256) void gemm_tile_kernel(const unsigned short* __restrict__ A,
                                                        const unsigned short* __restrict__ B0,
                                                        const unsigned short* __restrict__ B1,
                                                        unsigned short* __restrict__ C0,
                                                        unsigned short* __restrict__ C1,
                                                        int N) {
    __shared__ unsigned short As[TILE * DIM];  // 32 KB (tile contiguous in global)
    __shared__ unsigned short Bs[TILE * DIM];  // 32 KB
    int w = threadIdx.x >> 6;
    int lane = threadIdx.x & 63;
    int tm = blockIdx.y, tn = blockIdx.x;
    const unsigned short* B = blockIdx.z ? B1 : B0;
    unsigned short* C = blockIdx.z ? C1 : C0;

    const char* ga = (const char*)(A + (size_t)tm * TILE * DIM);
    const char* gb = (const char*)(B + (size_t)tn * TILE * DIM);
#pragma unroll
    for (int it = 0; it < 8; ++it) {
        int off = (w * 8 + it) * 1024;  // wave-chunk of 1KB (64 lanes x 16B)
        async_copy16(ga + off + lane * 16, (char*)As + off);
        async_copy16(gb + off + lane * 16, (char*)Bs + off);
    }
    __syncthreads();

    int wm = (w & 1) * 64;
    int wn = (w >> 1) * 64;
    int quad = lane >> 4;
    int l15 = lane & 15;

    f32x4 acc[4][4] = {};
#pragma unroll
    for (int kk = 0; kk < 4; ++kk) {
        int kb = kk * 32 + quad * 8;
        bf16x8 af[4], bfr[4];
#pragma unroll
        for (int mi = 0; mi < 4; ++mi)
            af[mi] = *(const bf16x8*)&As[(wm + mi * 16 + l15) * DIM + kb];
#pragma unroll
        for (int ni = 0; ni < 4; ++ni)
            bfr[ni] = *(const bf16x8*)&Bs[(wn + ni * 16 + l15) * DIM + kb];
#pragma unroll
        for (int mi = 0; mi < 4; ++mi)
#pragma unroll
            for (int ni = 0; ni < 4; ++ni)
                acc[mi][ni] = __builtin_amdgcn_mfma_f32_16x16x32_bf16(af[mi], bfr[ni], acc[mi][ni], 0, 0, 0);
    }

#pragma unroll
    for (int mi = 0; mi < 4; ++mi) {
        int row0 = tm * TILE + wm + mi * 16 + quad * 4;
#pragma unroll
        for (int ni = 0; ni < 4; ++ni) {
            int col = tn * TILE + wn + ni * 16 + l15;
#pragma unroll
            for (int r = 0; r < 4; ++r)
                C[(size_t)(row0 + r) * N + col] = f32_to_bf16(acc[mi][ni][r]);
        }
    }
}

// Merged loss + FastAP: one block per row i.
// - loss: 16 sim elems/thread register-resident; block max via shfl + LDS;
//   second pass from registers. (VALU + HBM pipe)
// - fastap: two u32 histograms. hist_all: 2 u32 atomics/elem (2-way bank floor,
//   free). hist_pos: exec-masked, ~8 elems/row. Scan packs (pos<<32)|all.
// 4 barriers total. Emits contrib[i] = loss_i * (1 - reward_i).
__global__ __launch_bounds__(256) void lossap_kernel(const unsigned short* __restrict__ sim,
                                                     const unsigned short* __restrict__ gram,
                                                     const int* __restrict__ tcol,
                                                     const int* __restrict__ trow,
                                                     const int* __restrict__ rlab,
                                                     float* __restrict__ contrib,
                                                     int n) {
    __shared__ unsigned int histA[L_BINS];  // total weight (x65536 fixed point)
    __shared__ unsigned int histP[L_BINS];  // positive weight
    __shared__ unsigned long long wsum[4];
    __shared__ float pmx[4], nmx[4], lsum[4], apw[4];
    __shared__ int npw[4];
    int i = blockIdx.x;
    int t = threadIdx.x;
    int w = t >> 6, lane = t & 63;

    for (int b = t; b < L_BINS; b += 256) { histA[b] = 0u; histP[b] = 0u; }

    int myt = tcol[i];
    int li = rlab[i];
    const uint4* simv = (const uint4*)(sim + (size_t)i * n);
    const uint4* grav = (const uint4*)(gram + (size_t)i * n);
    const int4* trv = (const int4*)trow;
    const int4* rlv = (const int4*)rlab;

    // Issue ALL global loads up front (sim row, gram row, both label arrays)
    // so HBM latency hides under hist-zero + maxima pass.
    uint4 spk[2], gpk[2];
    int4 tl[4], rl[4];
#pragma unroll
    for (int vv = 0; vv < 2; ++vv) {
        int vi = vv * 256 + t;
        spk[vv] = simv[vi];
        gpk[vv] = grav[vi];
        tl[2 * vv] = trv[2 * vi];
        tl[2 * vv + 1] = trv[2 * vi + 1];
        rl[2 * vv] = rlv[2 * vi];
        rl[2 * vv + 1] = rlv[2 * vi + 1];
    }

    // Pass 1: per-thread pos/neg maxima + selection masks from sim.
    float pmax = -3e38f, nmax = -3e38f;
    unsigned int posm = 0, negm = 0;
#pragma unroll
    for (int vv = 0; vv < 2; ++vv) {
        int vi = vv * 256 + t;
        float s[8];
        unpack8(spk[vv], s);
        int lab[8] = {tl[2 * vv].x, tl[2 * vv].y, tl[2 * vv].z, tl[2 * vv].w,
                      tl[2 * vv + 1].x, tl[2 * vv + 1].y, tl[2 * vv + 1].z, tl[2 * vv + 1].w};
#pragma unroll
        for (int k = 0; k < 8; ++k) {
            int j = vi * 8 + k;
            bool same = (lab[k] == myt);
            bool posf = same && (j != i);
            if (posf) pmax = fmaxf(pmax, s[k]);
            if (!same) nmax = fmaxf(nmax, s[k]);
            posm |= ((unsigned int)posf) << (vv * 8 + k);
            negm |= ((unsigned int)(!same)) << (vv * 8 + k);
        }
    }
    __syncthreads();  // hist zeroed

    // FastAP histogram: 2 u32 atomics/elem (+ rare exec-masked pos atomics).
    int npos = 0;
#pragma unroll
    for (int vv = 0; vv < 2; ++vv) {
        int vi = vv * 256 + t;
        float s[8];
        unpack8(gpk[vv], s);
        int lab[8] = {rl[2 * vv].x, rl[2 * vv].y, rl[2 * vv].z, rl[2 * vv].w,
                      rl[2 * vv + 1].x, rl[2 * vv + 1].y, rl[2 * vv + 1].z, rl[2 * vv + 1].w};
#pragma unroll
        for (int k = 0; k < 8; ++k) {
            int j = vi * 8 + k;
            float d2 = fminf(fmaxf(2.f - 2.f * s[k], 0.f), 4.f);
            float tt = d2 * 400.0f;  // / (4/1600)
            float fl = floorf(tt);
            int i0 = (int)fl;
            if (i0 > L_BINS - 1) i0 = L_BINS - 1;
            int i1 = i0 + 1;
            if (i1 > L_BINS - 1) i1 = L_BINS - 1;
            unsigned int w1 = (unsigned int)((tt - fl) * 65536.0f);
            unsigned int w0 = 65536u - w1;
            bool diag = (j == i);
            if (diag) { w0 = 0u; w1 = 0u; }
            bool posf = (lab[k] == li) && !diag;
            atomicAdd(&histA[i0], w0);
            atomicAdd(&histA[i1], w1);
            if (posf) {
                atomicAdd(&histP[i0], w0);
                atomicAdd(&histP[i1], w1);
                npos += 1;
            }
        }
    }

    // Wave maxima reduce (VALU, overlaps atomic drain).
#pragma unroll
    for (int off = 32; off > 0; off >>= 1) {
        pmax = fmaxf(pmax, __shfl_xor(pmax, off));
        nmax = fmaxf(nmax, __shfl_xor(nmax, off));
    }
    if (lane == 0) { pmx[w] = pmax; nmx[w] = nmax; }
    __syncthreads();  // atomics complete + wave maxima visible

    pmax = fmaxf(fmaxf(pmx[0], pmx[1]), fmaxf(pmx[2], pmx[3]));
    nmax = fmaxf(fmaxf(nmx[0], nmx[1]), fmaxf(nmx[2], nmx[3]));

    // Pass 2: loss sums from registers.
    float thr_n = nmax + 0.1f;               // pos selected when sim < neg_max + margin
    float thr_p = fmaxf(0.6f, pmax) - 0.1f;  // neg selected when sim > thr
    float pl = 0.f, nl = 0.f;
#pragma unroll
    for (int vv = 0; vv < 2; ++vv) {
        float s[8];
        unpack8(spk[vv], s);
#pragma unroll
        for (int k = 0; k < 8; ++k) {
            int bit = vv * 8 + k;
            bool posf = (posm >> bit) & 1u;
            bool negf = (negm >> bit) & 1u;
            pl += (posf && s[k] < thr_n) ? 1.f - s[k] : 0.f;
            nl += (negf && s[k] > thr_p) ? s[k] : 0.f;
        }
    }
    float tot = pl + nl;
#pragma unroll
    for (int off = 32; off > 0; off >>= 1) tot += __shfl_xor(tot, off);

    // Chunked scan: 7 bins/thread; shuffle inclusive scan of thread totals.
    // Pack (pos<<32)|all so one u64 scan covers both cumsums (no carry between
    // halves: total all-weight per row = 4095*65536 < 2^32).
    const int CH = 7;
    int base = t * CH;
    unsigned long long lc[CH];
    unsigned long long run = 0ull;
#pragma unroll
    for (int k = 0; k < CH; ++k) {
        int idx = base + k;
        unsigned long long h = (idx < L_BINS)
            ? (((unsigned long long)histP[idx] << 32) | (unsigned long long)histA[idx])
            : 0ull;
        run += h;
        lc[k] = run;
    }
    unsigned long long tsum = run;
    unsigned long long sc = tsum;
#pragma unroll
    for (int off = 1; off < 64; off <<= 1) {
        unsigned long long v2 = __shfl_up(sc, off);
        if (lane >= off) sc += v2;
    }
    if (lane == 63) wsum[w] = sc;
    if (lane == 0) lsum[w] = tot;
    __syncthreads();
    unsigned long long woff = 0ull;
    for (int ww = 0; ww < w; ++ww) woff += wsum[ww];
    unsigned long long throff = woff + sc - tsum;  // exclusive offset for this thread

    float ap = 0.f;
#pragma unroll
    for (int k = 0; k < CH; ++k) {
        int idx = base + k;
        if (idx < L_BINS) {
            unsigned int hp = histP[idx];
            if (hp) {
                unsigned long long cum = lc[k] + throff;
                unsigned int Hp = (unsigned int)(cum >> 32);
                unsigned int Ha = (unsigned int)cum;
                ap += (float)hp * (float)Hp / (float)Ha;
            }
        }
    }
#pragma unroll
    for (int off = 32; off > 0; off >>= 1) {
        ap += __shfl_xor(ap, off);
        npos += __shfl_xor(npos, off);
    }
    if (lane == 0) { apw[w] = ap; npw[w] = npos; }
    __syncthreads();
    if (t == 0) {
        float loss_i = (pmax > -1e30f) ? (lsum[0] + lsum[1] + lsum[2] + lsum[3]) : 0.f;
        float A = apw[0] + apw[1] + apw[2] + apw[3];
        int np = npw[0] + npw[1] + npw[2] + npw[3];
        float reward = (np > 0) ? A * (1.0f / 65536.0f) / (float)np : 0.f;
        contrib[i] = loss_i * (1.f - reward);
    }
}

__global__ __launch_bounds__(256) void final_kernel(const float* __restrict__ contrib,
                                                    float* __restrict__ out, int n) {
    __shared__ float r[256];
    int t = threadIdx.x;
    float s = 0.f;
    for (int j = t; j < n; j += 256) s += contrib[j];
    r[t] = s;
    __syncthreads();
    for (int off = 128; off > 0; off >>= 1) {
        if (t < off) r[t] += r[t + off];
        __syncthreads();
    }
    if (t == 0) out[0] = r[0] / (float)n;
}

extern "C" void kernel_launch(void* const* d_in, const int* in_sizes, int n_in,
                              void* d_out, int out_size, void* d_ws, size_t ws_size,
                              hipStream_t stream) {
    const float* inputs_col = (const float*)d_in[0];
    const int* targets_col = (const int*)d_in[1];
    const float* inputs_row = (const float*)d_in[2];
    const int* targets_row = (const int*)d_in[3];
    const int* reward_labels = (const int*)d_in[4];
    float* out = (float*)d_out;

    const int n = N_ROWS, m = N_ROWS, d = DIM;
    char* ws = (char*)d_ws;
    const size_t MB = 1048576;
    unsigned short* simbuf = (unsigned short*)ws;                 // 32 MB
    unsigned short* grambuf = (unsigned short*)(ws + 32 * MB);    // 32 MB
    unsigned short* Abf = (unsigned short*)(ws + 64 * MB);        // 1 MB
    unsigned short* Rbf = (unsigned short*)(ws + 65 * MB);        // 1 MB
    float* contrib = (float*)(ws + 66 * MB);

    // 1) f32 -> bf16 (both arrays, one launch)
    cvt2_kernel<<<512, 256, 0, stream>>>((const float4*)inputs_col, (const float4*)inputs_row,
                                         (ushort4*)Abf, (ushort4*)Rbf, n * d / 4);

    // 2) sim = col@row^T and gram = col@col^T in one launch
    dim3 ggrid(n / TILE, n / TILE, 2);
    gemm_tile_kernel<<<ggrid, 256, 0, stream>>>(Abf, Rbf, Abf, simbuf, grambuf, m);

    // 3) merged per-row loss + FastAP reward -> contrib[i]
    lossap_kernel<<<n, 256, 0, stream>>>(simbuf, grambuf, targets_col, targets_row,
                                         reward_labels, contrib, n);

    // 4) final scalar
    final_kernel<<<1, 256, 0, stream>>>(contrib, out, n);
}